// Round 4
// baseline (1405.683 us; speedup 1.0000x reference)
//
#include <hip/hip_runtime.h>

constexpr int NCAMS   = 6;
constexpr int EMB     = 256;
constexpr int NGROUPS = 8;
constexpr int NLVL    = 4;
constexpr int NPTS    = 13;
constexpr int NPAIR   = NPTS * NCAMS;   // 78
constexpr int NWAVES  = 8;              // waves per block

__global__ __launch_bounds__(512, 8)
void dfa_kernel(const float* __restrict__ value,
                const int*   __restrict__ shapes,   // (6,4,2) — cam0 rows used
                const int*   __restrict__ starts,   // (6,4)
                const float* __restrict__ loc,      // (B,A,P,6,2)
                const float* __restrict__ attw,     // (B,A,P,6,4,8)
                float*       __restrict__ out,      // (B,A,256)
                int A, int per_cam)
{
    const int tid  = threadIdx.x;
    const int wv   = tid >> 6;      // wave id 0..7
    const int lane = tid & 63;
    const int b = blockIdx.x / A;
    const int a = blockIdx.x - b * A;

    __shared__ int   sH[NLVL], sW[NLVL], sS[NLVL];
    __shared__ float red[NWAVES][EMB];
    if (tid < NLVL) {
        sH[tid] = shapes[tid * 2 + 0];
        sW[tid] = shapes[tid * 2 + 1];
        sS[tid] = starts[tid];
    }
    __syncthreads();

    const int g = lane >> 3;        // group for channels 4*lane..4*lane+3
    const long ba = (long)b * A + a;
    const float* locp = loc  + ba * (NPTS * NCAMS * 2);
    const float* awp  = attw + ba * (NPTS * NCAMS * NLVL * NGROUPS) + g;

    float4 acc = make_float4(0.f, 0.f, 0.f, 0.f);

    for (int pair = wv; pair < NPAIR; pair += NWAVES) {
        const int p = pair / NCAMS;
        const int c = pair - p * NCAMS;
        const float lw = locp[pair * 2 + 0];
        const float lh = locp[pair * 2 + 1];
        const float* vb = value + ((long)(b * NCAMS + c) * per_cam) * EMB + lane * 4;
        const float* awpc = awp + pair * (NLVL * NGROUPS);

        #pragma unroll
        for (int lvl = 0; lvl < NLVL; ++lvl) {
            const int H = sH[lvl], W = sW[lvl], S = sS[lvl];
            const float hf = lh * (float)H - 0.5f;
            const float wf = lw * (float)W - 0.5f;
            const float h0f = floorf(hf), w0f = floorf(wf);
            const float dh = hf - h0f, dw = wf - w0f;
            const int h0 = (int)h0f, w0 = (int)w0f;
            const int h1 = h0 + 1,  w1 = w0 + 1;

            const float aw = awpc[lvl * NGROUPS];

            float w00 = (1.f - dh) * (1.f - dw) * aw;
            float w01 = (1.f - dh) * dw         * aw;
            float w10 = dh         * (1.f - dw) * aw;
            float w11 = dh         * dw         * aw;

            const bool vh0 = (unsigned)h0 < (unsigned)H;
            const bool vh1 = (unsigned)h1 < (unsigned)H;
            const bool vw0 = (unsigned)w0 < (unsigned)W;
            const bool vw1 = (unsigned)w1 < (unsigned)W;
            w00 = (vh0 && vw0) ? w00 : 0.f;
            w01 = (vh0 && vw1) ? w01 : 0.f;
            w10 = (vh1 && vw0) ? w10 : 0.f;
            w11 = (vh1 && vw1) ? w11 : 0.f;

            const int h0c = min(max(h0, 0), H - 1);
            const int h1c = min(max(h1, 0), H - 1);
            const int w0c = min(max(w0, 0), W - 1);
            const int w1c = min(max(w1, 0), W - 1);

            const float* r0 = vb + (long)(S + h0c * W) * EMB;
            const float* r1 = vb + (long)(S + h1c * W) * EMB;

            const float4 v00 = *(const float4*)(r0 + (long)w0c * EMB);
            const float4 v01 = *(const float4*)(r0 + (long)w1c * EMB);
            const float4 v10 = *(const float4*)(r1 + (long)w0c * EMB);
            const float4 v11 = *(const float4*)(r1 + (long)w1c * EMB);

            acc.x += v00.x * w00 + v01.x * w01 + v10.x * w10 + v11.x * w11;
            acc.y += v00.y * w00 + v01.y * w01 + v10.y * w10 + v11.y * w11;
            acc.z += v00.z * w00 + v01.z * w01 + v10.z * w10 + v11.z * w11;
            acc.w += v00.w * w00 + v01.w * w01 + v10.w * w10 + v11.w * w11;
        }
    }

    *(float4*)&red[wv][lane * 4] = acc;
    __syncthreads();

    if (tid < EMB) {
        float o = red[0][tid];
        #pragma unroll
        for (int w = 1; w < NWAVES; ++w) o += red[w][tid];
        out[ba * EMB + tid] = o;
    }
}

extern "C" void kernel_launch(void* const* d_in, const int* in_sizes, int n_in,
                              void* d_out, int out_size, void* d_ws, size_t ws_size,
                              hipStream_t stream) {
    const float* value  = (const float*)d_in[0];
    const int*   shapes = (const int*)d_in[1];
    const int*   starts = (const int*)d_in[2];
    const float* loc    = (const float*)d_in[3];
    const float* attw   = (const float*)d_in[4];
    float*       out    = (float*)d_out;

    const int B = 2;
    const int A = out_size / (EMB * B);                  // 900
    const int per_cam = in_sizes[0] / (B * EMB * NCAMS); // 14960

    dim3 grid(B * A);
    dim3 block(512);
    dfa_kernel<<<grid, block, 0, stream>>>(value, shapes, starts, loc, attw, out,
                                           A, per_cam);
}

// Round 6
// 1404.023 us; speedup vs baseline: 1.0012x; 1.0012x over previous
//
#include <hip/hip_runtime.h>

constexpr int NCAMS   = 6;
constexpr int EMB     = 256;
constexpr int NGROUPS = 8;
constexpr int NLVL    = 4;
constexpr int NPTS    = 13;
constexpr int NPAIR   = NPTS * NCAMS;   // 78

// 256 threads / 4 waves per block. __launch_bounds__(256,8): 8 waves/EU min
// -> 64-VGPR budget; this kernel compiled to 56 VGPRs at (256,4), so it fits
// WITHOUT spilling. (512,8) forced 32 VGPRs and 2.4 GB of scratch writes.
__global__ __launch_bounds__(256, 8)
void dfa_kernel(const float* __restrict__ value,
                const int*   __restrict__ shapes,   // (6,4,2) — cam0 rows used
                const int*   __restrict__ starts,   // (6,4)
                const float* __restrict__ loc,      // (B,A,P,6,2)
                const float* __restrict__ attw,     // (B,A,P,6,4,8)
                float*       __restrict__ out,      // (B,A,256)
                int A, int per_cam)
{
    const int tid  = threadIdx.x;
    const int wv   = tid >> 6;      // wave id 0..3
    const int lane = tid & 63;
    const int b = blockIdx.x / A;
    const int a = blockIdx.x - b * A;

    __shared__ int   sH[NLVL], sW[NLVL], sS[NLVL];
    __shared__ float red[4][EMB];
    if (tid < NLVL) {
        sH[tid] = shapes[tid * 2 + 0];
        sW[tid] = shapes[tid * 2 + 1];
        sS[tid] = starts[tid];
    }
    __syncthreads();

    const int g = lane >> 3;        // group for channels 4*lane..4*lane+3
    const long ba = (long)b * A + a;
    const float* locp = loc  + ba * (NPTS * NCAMS * 2);
    const float* awp  = attw + ba * (NPTS * NCAMS * NLVL * NGROUPS) + g;

    float4 acc = make_float4(0.f, 0.f, 0.f, 0.f);

    for (int pair = wv; pair < NPAIR; pair += 4) {
        const int p = pair / NCAMS;
        const int c = pair - p * NCAMS;
        const float lw = locp[pair * 2 + 0];
        const float lh = locp[pair * 2 + 1];
        const float* vb = value + ((long)(b * NCAMS + c) * per_cam) * EMB + lane * 4;
        const float* awpc = awp + pair * (NLVL * NGROUPS);

        #pragma unroll
        for (int lvl = 0; lvl < NLVL; ++lvl) {
            const int H = sH[lvl], W = sW[lvl], S = sS[lvl];
            const float hf = lh * (float)H - 0.5f;
            const float wf = lw * (float)W - 0.5f;
            const float h0f = floorf(hf), w0f = floorf(wf);
            const float dh = hf - h0f, dw = wf - w0f;
            const int h0 = (int)h0f, w0 = (int)w0f;
            const int h1 = h0 + 1,  w1 = w0 + 1;

            const float aw = awpc[lvl * NGROUPS];

            float w00 = (1.f - dh) * (1.f - dw) * aw;
            float w01 = (1.f - dh) * dw         * aw;
            float w10 = dh         * (1.f - dw) * aw;
            float w11 = dh         * dw         * aw;

            const bool vh0 = (unsigned)h0 < (unsigned)H;
            const bool vh1 = (unsigned)h1 < (unsigned)H;
            const bool vw0 = (unsigned)w0 < (unsigned)W;
            const bool vw1 = (unsigned)w1 < (unsigned)W;
            w00 = (vh0 && vw0) ? w00 : 0.f;
            w01 = (vh0 && vw1) ? w01 : 0.f;
            w10 = (vh1 && vw0) ? w10 : 0.f;
            w11 = (vh1 && vw1) ? w11 : 0.f;

            const int h0c = min(max(h0, 0), H - 1);
            const int h1c = min(max(h1, 0), H - 1);
            const int w0c = min(max(w0, 0), W - 1);
            const int w1c = min(max(w1, 0), W - 1);

            const float* r0 = vb + (long)(S + h0c * W) * EMB;
            const float* r1 = vb + (long)(S + h1c * W) * EMB;

            const float4 v00 = *(const float4*)(r0 + (long)w0c * EMB);
            const float4 v01 = *(const float4*)(r0 + (long)w1c * EMB);
            const float4 v10 = *(const float4*)(r1 + (long)w0c * EMB);
            const float4 v11 = *(const float4*)(r1 + (long)w1c * EMB);

            acc.x += v00.x * w00 + v01.x * w01 + v10.x * w10 + v11.x * w11;
            acc.y += v00.y * w00 + v01.y * w01 + v10.y * w10 + v11.y * w11;
            acc.z += v00.z * w00 + v01.z * w01 + v10.z * w10 + v11.z * w11;
            acc.w += v00.w * w00 + v01.w * w01 + v10.w * w10 + v11.w * w11;
        }
    }

    *(float4*)&red[wv][lane * 4] = acc;
    __syncthreads();

    const float o = red[0][tid] + red[1][tid] + red[2][tid] + red[3][tid];
    out[ba * EMB + tid] = o;
}

extern "C" void kernel_launch(void* const* d_in, const int* in_sizes, int n_in,
                              void* d_out, int out_size, void* d_ws, size_t ws_size,
                              hipStream_t stream) {
    const float* value  = (const float*)d_in[0];
    const int*   shapes = (const int*)d_in[1];
    const int*   starts = (const int*)d_in[2];
    const float* loc    = (const float*)d_in[3];
    const float* attw   = (const float*)d_in[4];
    float*       out    = (float*)d_out;

    const int B = 2;
    const int A = out_size / (EMB * B);                  // 900
    const int per_cam = in_sizes[0] / (B * EMB * NCAMS); // 14960

    dim3 grid(B * A);
    dim3 block(256);
    dfa_kernel<<<grid, block, 0, stream>>>(value, shapes, starts, loc, attw, out,
                                           A, per_cam);
}

// Round 7
// 449.542 us; speedup vs baseline: 3.1269x; 3.1232x over previous
//
#include <hip/hip_runtime.h>

constexpr int NCAMS   = 6;
constexpr int EMB     = 256;
constexpr int NGROUPS = 8;
constexpr int NLVL    = 4;
constexpr int NPTS    = 13;
constexpr int NPAIR   = NPTS * NCAMS;   // 78
constexpr int SPLIT   = 4;              // blocks per anchor (gridDim.y)

// NOTE: min-waves hints are poison here. (512,8) AND (256,8) both made hipcc
// clamp to 32 VGPRs and spill ~2.4 GB to scratch (rounds 4/6). (256,4) gives
// 56 VGPRs, zero spill. Occupancy is raised via MORE BLOCKS instead.
template <bool USE_ATOMIC>
__global__ __launch_bounds__(256, 4)
void dfa_kernel(const float* __restrict__ value,
                const int*   __restrict__ shapes,   // (6,4,2) — cam0 rows used
                const int*   __restrict__ starts,   // (6,4)
                const float* __restrict__ loc,      // (B,A,P,6,2)
                const float* __restrict__ attw,     // (B,A,P,6,4,8)
                float*       __restrict__ dst,      // ws partials or out
                int A, int per_cam)
{
    const int tid   = threadIdx.x;
    const int wv    = tid >> 6;      // wave id 0..3
    const int lane  = tid & 63;
    const int split = blockIdx.y;    // 0..SPLIT-1
    const int b = blockIdx.x / A;
    const int a = blockIdx.x - b * A;

    __shared__ int   sH[NLVL], sW[NLVL], sS[NLVL];
    __shared__ float red[4][EMB];
    if (tid < NLVL) {
        sH[tid] = shapes[tid * 2 + 0];
        sW[tid] = shapes[tid * 2 + 1];
        sS[tid] = starts[tid];
    }
    __syncthreads();

    const int g = lane >> 3;        // group for channels 4*lane..4*lane+3
    const long ba = (long)b * A + a;
    const float* locp = loc  + ba * (NPTS * NCAMS * 2);
    const float* awp  = attw + ba * (NPTS * NCAMS * NLVL * NGROUPS) + g;

    float4 acc = make_float4(0.f, 0.f, 0.f, 0.f);

    // worker id = wv + 4*split in [0,16); pairs strided by 16
    for (int pair = wv + (split << 2); pair < NPAIR; pair += 4 * SPLIT) {
        const int p = pair / NCAMS;
        const int c = pair - p * NCAMS;
        const float lw = locp[pair * 2 + 0];
        const float lh = locp[pair * 2 + 1];
        const float* vb = value + ((long)(b * NCAMS + c) * per_cam) * EMB + lane * 4;
        const float* awpc = awp + pair * (NLVL * NGROUPS);

        #pragma unroll
        for (int lvl = 0; lvl < NLVL; ++lvl) {
            const int H = sH[lvl], W = sW[lvl], S = sS[lvl];
            const float hf = lh * (float)H - 0.5f;
            const float wf = lw * (float)W - 0.5f;
            const float h0f = floorf(hf), w0f = floorf(wf);
            const float dh = hf - h0f, dw = wf - w0f;
            const int h0 = (int)h0f, w0 = (int)w0f;
            const int h1 = h0 + 1,  w1 = w0 + 1;

            const float aw = awpc[lvl * NGROUPS];

            float w00 = (1.f - dh) * (1.f - dw) * aw;
            float w01 = (1.f - dh) * dw         * aw;
            float w10 = dh         * (1.f - dw) * aw;
            float w11 = dh         * dw         * aw;

            const bool vh0 = (unsigned)h0 < (unsigned)H;
            const bool vh1 = (unsigned)h1 < (unsigned)H;
            const bool vw0 = (unsigned)w0 < (unsigned)W;
            const bool vw1 = (unsigned)w1 < (unsigned)W;
            w00 = (vh0 && vw0) ? w00 : 0.f;
            w01 = (vh0 && vw1) ? w01 : 0.f;
            w10 = (vh1 && vw0) ? w10 : 0.f;
            w11 = (vh1 && vw1) ? w11 : 0.f;

            const int h0c = min(max(h0, 0), H - 1);
            const int h1c = min(max(h1, 0), H - 1);
            const int w0c = min(max(w0, 0), W - 1);
            const int w1c = min(max(w1, 0), W - 1);

            const float* r0 = vb + (long)(S + h0c * W) * EMB;
            const float* r1 = vb + (long)(S + h1c * W) * EMB;

            const float4 v00 = *(const float4*)(r0 + (long)w0c * EMB);
            const float4 v01 = *(const float4*)(r0 + (long)w1c * EMB);
            const float4 v10 = *(const float4*)(r1 + (long)w0c * EMB);
            const float4 v11 = *(const float4*)(r1 + (long)w1c * EMB);

            acc.x += v00.x * w00 + v01.x * w01 + v10.x * w10 + v11.x * w11;
            acc.y += v00.y * w00 + v01.y * w01 + v10.y * w10 + v11.y * w11;
            acc.z += v00.z * w00 + v01.z * w01 + v10.z * w10 + v11.z * w11;
            acc.w += v00.w * w00 + v01.w * w01 + v10.w * w10 + v11.w * w11;
        }
    }

    *(float4*)&red[wv][lane * 4] = acc;
    __syncthreads();

    const float o = red[0][tid] + red[1][tid] + red[2][tid] + red[3][tid];
    if (USE_ATOMIC) {
        atomicAdd(&dst[ba * EMB + tid], o);
    } else {
        // partial[split][ba][tid]
        dst[((long)split * gridDim.x + ba) * EMB + tid] = o;
    }
}

__global__ __launch_bounds__(256, 4)
void reduce_kernel(const float* __restrict__ ws, float* __restrict__ out, int n4)
{
    const int i = blockIdx.x * blockDim.x + threadIdx.x;
    if (i >= n4) return;
    const float4* p = (const float4*)ws;
    float4 s = p[i];
    #pragma unroll
    for (int sp = 1; sp < SPLIT; ++sp) {
        const float4 q = p[(long)sp * n4 + i];
        s.x += q.x; s.y += q.y; s.z += q.z; s.w += q.w;
    }
    ((float4*)out)[i] = s;
}

__global__ void zero_kernel(float* __restrict__ out, int n4)
{
    const int i = blockIdx.x * blockDim.x + threadIdx.x;
    if (i < n4) ((float4*)out)[i] = make_float4(0.f, 0.f, 0.f, 0.f);
}

extern "C" void kernel_launch(void* const* d_in, const int* in_sizes, int n_in,
                              void* d_out, int out_size, void* d_ws, size_t ws_size,
                              hipStream_t stream) {
    const float* value  = (const float*)d_in[0];
    const int*   shapes = (const int*)d_in[1];
    const int*   starts = (const int*)d_in[2];
    const float* loc    = (const float*)d_in[3];
    const float* attw   = (const float*)d_in[4];
    float*       out    = (float*)d_out;

    const int B = 2;
    const int A = out_size / (EMB * B);                  // 900
    const int per_cam = in_sizes[0] / (B * EMB * NCAMS); // 14960
    const int BA = B * A;
    const size_t need = (size_t)SPLIT * BA * EMB * sizeof(float);

    dim3 grid(BA, SPLIT);
    dim3 block(256);

    if (ws_size >= need) {
        float* ws = (float*)d_ws;
        dfa_kernel<false><<<grid, block, 0, stream>>>(value, shapes, starts, loc,
                                                      attw, ws, A, per_cam);
        const int n4 = BA * EMB / 4;
        reduce_kernel<<<(n4 + 255) / 256, 256, 0, stream>>>(ws, out, n4);
    } else {
        const int n4 = BA * EMB / 4;
        zero_kernel<<<(n4 + 255) / 256, 256, 0, stream>>>(out, n4);
        dfa_kernel<true><<<grid, block, 0, stream>>>(value, shapes, starts, loc,
                                                     attw, out, A, per_cam);
    }
}